// Round 1
// baseline (204.574 us; speedup 1.0000x reference)
//
#include <hip/hip_runtime.h>

// Problem constants (from reference): B=128, V=300, MAX_VISITS=510, D=256,
// VOCAB=50000, MAX_DAYS=365. D/4 = 64 float4 per row; timescales = 128 fp32.
#define MAXV 510
#define D4 64  // D/4

// Kernel 1: out[p, s, :] = pad_embedding  for all (p,s).
__global__ __launch_bounds__(256) void fill_pad(float4* __restrict__ out,
                                                const float4* __restrict__ pad,
                                                int n4) {
    int idx = blockIdx.x * blockDim.x + threadIdx.x;
    if (idx < n4) {
        out[idx] = pad[idx & (D4 - 1)];
    }
}

// Kernel 2: one wave per visit. Lane l owns dims [4l, 4l+4).
// Segment [lo,hi) of codes for visit v found by binary search on sorted c2v.
__global__ __launch_bounds__(256) void visit_kernel(
    const int* __restrict__ all_codes,
    const int* __restrict__ c2v,
    const int* __restrict__ person,
    const int* __restrict__ slot,
    const float* __restrict__ times,
    const float4* __restrict__ emb,   // [VOCAB, D4]
    const float4* __restrict__ tsc,   // [32] = 128 timescales as float4
    float4* __restrict__ out,         // [B, MAXV, D4]
    int total_codes, int total_visits)
{
    __shared__ int s_off[5];
    const int tid = threadIdx.x;
    const int vbase = blockIdx.x * 4;

    if (tid < 5) {
        const int v = vbase + tid;
        int lo = 0, hi = total_codes;
        while (lo < hi) {             // lower_bound(c2v, v)
            int mid = (lo + hi) >> 1;
            if (c2v[mid] < v) lo = mid + 1; else hi = mid;
        }
        s_off[tid] = lo;
    }
    __syncthreads();

    const int w = tid >> 6;           // wave within block: 0..3
    const int lane = tid & 63;
    const int v = vbase + w;
    if (v >= total_visits) return;

    const int lo = s_off[w];
    const int hi = s_off[w + 1];

    float4 acc = make_float4(0.f, 0.f, 0.f, 0.f);
    for (int i = lo; i < hi; ++i) {
        const int code = all_codes[i];            // wave-uniform load
        const float4 e = emb[code * D4 + lane];   // coalesced 1KB row read
        acc.x += e.x; acc.y += e.y; acc.z += e.z; acc.w += e.w;
    }

    float t = times[v];
    t = fminf(fmaxf(t, 0.f), 364.f);              // clip(times, 0, MAX_DAYS-1)
    const float4 ts = tsc[lane & 31];
    float4 te;
    if (lane < 32) {
        te.x = sinf(t * ts.x); te.y = sinf(t * ts.y);
        te.z = sinf(t * ts.z); te.w = sinf(t * ts.w);
    } else {
        te.x = cosf(t * ts.x); te.y = cosf(t * ts.y);
        te.z = cosf(t * ts.z); te.w = cosf(t * ts.w);
    }

    const int p = person[v];
    const int s = slot[v];
    out[(p * MAXV + s) * D4 + lane] =
        make_float4(acc.x + te.x, acc.y + te.y, acc.z + te.z, acc.w + te.w);
}

extern "C" void kernel_launch(void* const* d_in, const int* in_sizes, int n_in,
                              void* d_out, int out_size, void* d_ws, size_t ws_size,
                              hipStream_t stream) {
    const int*   all_codes = (const int*)d_in[0];
    const int*   c2v       = (const int*)d_in[1];
    const int*   person    = (const int*)d_in[2];
    const int*   slot      = (const int*)d_in[3];
    const float* times     = (const float*)d_in[4];
    const float* emb       = (const float*)d_in[5];
    const float* pad       = (const float*)d_in[6];
    const float* tsc       = (const float*)d_in[7];

    const int total_codes  = in_sizes[0];
    const int total_visits = in_sizes[2];

    // 1) pad fill over entire output (vectorized float4)
    const int n4 = out_size / 4;
    fill_pad<<<(n4 + 255) / 256, 256, 0, stream>>>((float4*)d_out,
                                                   (const float4*)pad, n4);

    // 2) per-visit segment-sum + time embedding, scattered write
    const int nblocks = (total_visits + 3) / 4;
    visit_kernel<<<nblocks, 256, 0, stream>>>(all_codes, c2v, person, slot, times,
                                              (const float4*)emb,
                                              (const float4*)tsc,
                                              (float4*)d_out,
                                              total_codes, total_visits);
}

// Round 2
// 174.536 us; speedup vs baseline: 1.1721x; 1.1721x over previous
//
#include <hip/hip_runtime.h>

// B=128, V=300, MAX_VISITS=510, D=256, VOCAB=50000, MAX_DAYS=365.
#define MAXV 510
#define D4 64  // D/4 float4 per row

// ---- Kernel 1: init inverse map to -1 ----
__global__ __launch_bounds__(256) void init_inv(int* __restrict__ inv, int nslots) {
    int i = blockIdx.x * blockDim.x + threadIdx.x;
    if (i < nslots) inv[i] = -1;
}

// ---- Kernel 2: scatter slot->visit inverse map + per-visit segment offsets ----
__global__ __launch_bounds__(256) void build_maps(
    const int* __restrict__ c2v,
    const int* __restrict__ person,
    const int* __restrict__ slot,
    int* __restrict__ inv,     // [B*MAXV]
    int* __restrict__ off,     // [total_visits+1]
    int total_codes, int total_visits)
{
    int v = blockIdx.x * blockDim.x + threadIdx.x;
    if (v >= total_visits) return;
    inv[person[v] * MAXV + slot[v]] = v;
    // lower_bound(c2v, v) over sorted segment ids (c2v fits in L2: 1.7 MB)
    int lo = 0, hi = total_codes;
    while (lo < hi) {
        int m = (lo + hi) >> 1;
        if (c2v[m] < v) lo = m + 1; else hi = m;
    }
    off[v] = lo;
    if (v == 0) off[total_visits] = total_codes;
}

// ---- Kernel 3: fused pad-fill + segment-sum + time embedding ----
// One wave per output slot; lane l owns dims [4l, 4l+4).
__global__ __launch_bounds__(256) void fused_kernel(
    const int* __restrict__ all_codes,
    const float* __restrict__ times,
    const float4* __restrict__ emb,   // [VOCAB, D4]
    const float4* __restrict__ pad,   // [D4]
    const float4* __restrict__ tsc,   // [32] = 128 timescales
    const int* __restrict__ inv,      // [nslots]
    const int* __restrict__ off,      // [total_visits+1]
    float4* __restrict__ out,         // [nslots, D4]
    int nslots)
{
    const int tid = threadIdx.x;
    const int w = tid >> 6;
    const int lane = tid & 63;
    const int slot_id = blockIdx.x * 4 + w;
    if (slot_id >= nslots) return;

    const int v = inv[slot_id];
    if (v < 0) {
        out[slot_id * D4 + lane] = pad[lane];   // pad slot
        return;
    }

    const int lo = off[v];
    const int hi = off[v + 1];
    const int cnt = hi - lo;

    float4 acc = make_float4(0.f, 0.f, 0.f, 0.f);
    // Preload codes with one vectorized lane-load, broadcast via shfl so all
    // row gathers issue back-to-back (high MLP, no dependent-load chain).
    for (int base = 0; base < cnt; base += 64) {
        const int n = min(cnt - base, 64);
        const int mycode = (lane < n) ? all_codes[lo + base + lane] : 0;
        for (int j = 0; j < n; ++j) {
            const int c = __shfl(mycode, j);
            const float4 e = emb[c * D4 + lane];
            acc.x += e.x; acc.y += e.y; acc.z += e.z; acc.w += e.w;
        }
    }

    float t = times[v];
    t = fminf(fmaxf(t, 0.f), 364.f);
    const float4 ts = tsc[lane & 31];
    float4 te;
    if (lane < 32) {
        te.x = sinf(t * ts.x); te.y = sinf(t * ts.y);
        te.z = sinf(t * ts.z); te.w = sinf(t * ts.w);
    } else {
        te.x = cosf(t * ts.x); te.y = cosf(t * ts.y);
        te.z = cosf(t * ts.z); te.w = cosf(t * ts.w);
    }

    out[slot_id * D4 + lane] =
        make_float4(acc.x + te.x, acc.y + te.y, acc.z + te.z, acc.w + te.w);
}

extern "C" void kernel_launch(void* const* d_in, const int* in_sizes, int n_in,
                              void* d_out, int out_size, void* d_ws, size_t ws_size,
                              hipStream_t stream) {
    const int*   all_codes = (const int*)d_in[0];
    const int*   c2v       = (const int*)d_in[1];
    const int*   person    = (const int*)d_in[2];
    const int*   slot      = (const int*)d_in[3];
    const float* times     = (const float*)d_in[4];
    const float* emb       = (const float*)d_in[5];
    const float* pad       = (const float*)d_in[6];
    const float* tsc       = (const float*)d_in[7];

    const int total_codes  = in_sizes[0];
    const int total_visits = in_sizes[2];
    const int nslots       = out_size / 256;   // B * MAXV

    int* inv = (int*)d_ws;                     // [nslots]
    int* off = inv + nslots;                   // [total_visits+1]

    init_inv<<<(nslots + 255) / 256, 256, 0, stream>>>(inv, nslots);

    build_maps<<<(total_visits + 255) / 256, 256, 0, stream>>>(
        c2v, person, slot, inv, off, total_codes, total_visits);

    fused_kernel<<<(nslots + 3) / 4, 256, 0, stream>>>(
        all_codes, times, (const float4*)emb, (const float4*)pad,
        (const float4*)tsc, inv, off, (float4*)d_out, nslots);
}